// Round 7
// baseline (1763.264 us; speedup 1.0000x reference)
//
#include <hip/hip_runtime.h>

#define HN  128
#define NPG 32
#define NT  512
#define NW  8      // waves per block; 1 wave == 1 graph
#define SPW 8      // graphs per wave (serial)

typedef float f4 __attribute__((ext_vector_type(4)));
typedef float f2 __attribute__((ext_vector_type(2)));

__device__ __forceinline__ float tanh_fast(float v) {
  // tanh(v) = 1 - 2/(1+exp(2v)); overflow->inf->+1, underflow->0->-1 (graceful)
  return 1.0f - 2.0f / (1.0f + __expf(2.0f * v));
}

__global__ __launch_bounds__(NT, 4) void gib_main(
    const float* __restrict__ x,  const float* __restrict__ W1,
    const float* __restrict__ b1, const float* __restrict__ W2,
    const float* __restrict__ b2, const float* __restrict__ gn,
    const float* __restrict__ un, const int* __restrict__ ei,
    float* __restrict__ out, float* __restrict__ ws,
    int G, long E, int epg)
{
  const int t  = threadIdx.x;
  const int wv = t >> 6;
  const int l  = t & 63;
  const int ng = l & 3;    // node group: nodes ng+4i, i=0..7
  const int cg = l >> 2;   // col group: cols 8cg..8cg+7  (cg in [0,16))

  __shared__ __align__(16) float W1s[HN * HN];   // 64 KB, plain [k][c]
  __shared__ float s_lp[NW][NPG], s_a0[NW][NPG];

  const long GL = (long)G * HN;

  // ---- stage W1 once (plain layout; reads below are conflict-free) ----
  #pragma unroll
  for (int r = 0; r < 8; ++r) {
    int s = r * NT + t;
    *(f4*)&W1s[s * 4] = *(const f4*)(W1 + s * 4);
  }
  __syncthreads();   // only block-wide barrier

  const long gbase = ((long)blockIdx.x * NW + wv) * SPW;

  for (int si = 0; si < SPW; ++si) {
    const long g = gbase + si;
    if (g >= G) break;
    const long nb = g * NPG;
    const float* xg = x + nb * HN;
    const float* ug = un + nb * HN;

    // ================= MLP: acc[8 nodes][8 cols] in registers =================
    f4 accA[8], accB[8];
    {
      f4 bA = *(const f4*)(b1 + 8 * cg);
      f4 bB = *(const f4*)(b1 + 8 * cg + 4);
      #pragma unroll
      for (int i = 0; i < 8; ++i) { accA[i] = bA; accB[i] = bB; }
    }
    #pragma unroll 2
    for (int kc = 0; kc < 32; ++kc) {
      f4 xv[8];
      #pragma unroll
      for (int i = 0; i < 8; ++i)
        xv[i] = *(const f4*)(xg + (ng + 4 * i) * HN + kc * 4);   // dedup'd across cg
      #pragma unroll
      for (int kk = 0; kk < 4; ++kk) {
        f4 wA = *(const f4*)&W1s[(kc * 4 + kk) * HN + 8 * cg];
        f4 wB = *(const f4*)&W1s[(kc * 4 + kk) * HN + 8 * cg + 4];
        #pragma unroll
        for (int i = 0; i < 8; ++i) {
          accA[i] += wA * xv[i][kk];
          accB[i] += wB * xv[i][kk];
        }
      }
    }

    // ---- epilogue: tanh -> W2 -> per-node logits, reduce across 16 cg lanes ----
    float z0[8], z1[8];
    {
      f4 w2a = *(const f4*)(W2 + 16 * cg);        // rows 8cg..8cg+1 (c0,c1 pairs)
      f4 w2b = *(const f4*)(W2 + 16 * cg + 4);
      f4 w2c = *(const f4*)(W2 + 16 * cg + 8);
      f4 w2d = *(const f4*)(W2 + 16 * cg + 12);
      #pragma unroll
      for (int i = 0; i < 8; ++i) {
        float h0 = tanh_fast(accA[i][0]), h1 = tanh_fast(accA[i][1]);
        float h2 = tanh_fast(accA[i][2]), h3 = tanh_fast(accA[i][3]);
        float h4 = tanh_fast(accB[i][0]), h5 = tanh_fast(accB[i][1]);
        float h6 = tanh_fast(accB[i][2]), h7 = tanh_fast(accB[i][3]);
        float a = h0*w2a[0] + h1*w2a[2] + h2*w2b[0] + h3*w2b[2]
                + h4*w2c[0] + h5*w2c[2] + h6*w2d[0] + h7*w2d[2];
        float b = h0*w2a[1] + h1*w2a[3] + h2*w2b[1] + h3*w2b[3]
                + h4*w2c[1] + h5*w2c[3] + h6*w2d[1] + h7*w2d[3];
        #pragma unroll
        for (int m = 4; m <= 32; m <<= 1) {
          a += __shfl_xor(a, m, 64);
          b += __shfl_xor(b, m, 64);
        }
        z0[i] = a; z1[i] = b;
      }
    }

    // ================= stats (lane owns features 2l, 2l+1; x now L2-hot) =======
    f2 mu, sd, iv;
    float r2acc;
    {
      float s10 = 0.f, s11 = 0.f, s20 = 0.f, s21 = 0.f;
      #pragma unroll 8
      for (int n = 0; n < NPG; ++n) {
        f2 v = *(const f2*)(xg + n * HN + 2 * l);
        s10 += v[0]; s11 += v[1];
        s20 = fmaf(v[0], v[0], s20);
        s21 = fmaf(v[1], v[1], s21);
      }
      float m0 = s10 * (1.f / NPG), m1 = s11 * (1.f / NPG);
      float v0 = fmaxf((s20 - s10 * m0) * (1.f / (NPG - 1)), 0.f);
      float v1 = fmaxf((s21 - s11 * m1) * (1.f / (NPG - 1)), 0.f);
      float sd0 = sqrtf(v0), sd1 = sqrtf(v1);
      float in0 = 1.f / (sd0 + 1e-7f), in1 = 1.f / (sd1 + 1e-7f);
      mu[0] = m0; mu[1] = m1;
      sd[0] = sd0; sd[1] = sd1;
      iv[0] = in0 * in0; iv[1] = in1 * in1;
      f2 ge; ge[0] = s10; ge[1] = s11;
      *(f2*)&out[g * HN + 2 * l] = ge;              // graph_emb
      float r0 = sd0 * in0, r1 = sd1 * in1;
      float rr = r0 * r0 + r1 * r1;
      #pragma unroll
      for (int m = 1; m <= 32; m <<= 1) rr += __shfl_xor(rr, m, 64);
      r2acc = rr;
    }

    // ================= softmax + gumbel (each lane: its 8 nodes) ==============
    float vSLN = 0.f, vSLN2 = 0.f, vpres = 0.f;
    {
      const float b20 = b2[0], b21 = b2[1];
      #pragma unroll
      for (int i = 0; i < 8; ++i) {
        const int n = ng + 4 * i;
        f2 gnr = *(const f2*)(gn + (nb + n) * 2);
        float za = z0[i] + b20, zb = z1[i] + b21;
        float zm = fmaxf(za, zb);
        float e0 = __expf(za - zm), e1 = __expf(zb - zm);
        float a0 = e0 / (e0 + e1), a1 = 1.f - a0;
        float q0 = a0 + gnr[0], q1 = a1 + gnr[1];
        float qm = fmaxf(q0, q1);
        float E0 = __expf(q0 - qm), E1 = __expf(q1 - qm);
        float lp = E0 / (E0 + E1), ln = 1.f - lp;
        if (cg == 0) { s_lp[wv][n] = lp; s_a0[wv][n] = a0; }
        vSLN += ln; vSLN2 += ln * ln; vpres += (a0 > 0.5f) ? 1.f : 0.f;
      }
      if (cg != 0) { vSLN = 0.f; vSLN2 = 0.f; vpres = 0.f; }
      #pragma unroll
      for (int m = 1; m <= 32; m <<= 1) {
        vSLN  += __shfl_xor(vSLN,  m, 64);
        vSLN2 += __shfl_xor(vSLN2, m, 64);
        vpres += __shfl_xor(vpres, m, 64);
      }
    }
    if (l < NPG)
      out[2 * GL + nb + l] = (s_lp[wv][l] > 0.5f) ? 1.0f : 0.0f;   // active

    // ================= T2 + noisy_emb (lane owns 2 features) ==================
    float tv = 0.f, A0 = 0.f, A1 = 0.f, B0 = 0.f, B1 = 0.f;
    #pragma unroll 4
    for (int n = 0; n < NPG; ++n) {
      f2 xv = *(const f2*)(xg + n * HN + 2 * l);   // L2-hot
      f2 uv = *(const f2*)(ug + n * HN + 2 * l);   // streamed
      float lpn = s_lp[wv][n];
      float lnn = 1.f - lpn;
      float d0 = xv[0] - mu[0], d1 = xv[1] - mu[1];
      tv = fmaf(lpn * lpn, fmaf(d0 * d0, iv[0], d1 * d1 * iv[1]), tv);
      A0 = fmaf(lpn, xv[0], A0); A1 = fmaf(lpn, xv[1], A1);
      B0 = fmaf(lnn, uv[0], B0); B1 = fmaf(lnn, uv[1], B1);
    }
    {
      f2 ne;
      ne[0] = fmaf(mu[0], vSLN, A0) + sd[0] * B0;
      ne[1] = fmaf(mu[1], vSLN, A1) + sd[1] * B1;
      *(f2*)&out[GL + g * HN + 2 * l] = ne;        // noisy_emb
    }
    #pragma unroll
    for (int m = 1; m <= 32; m <<= 1) tv += __shfl_xor(tv, m, 64);

    // ================= edges -> 2x2 adjacency; per-graph scalars ==============
    float c00 = 0.f, c01 = 0.f, c10 = 0.f, c11 = 0.f;
    for (int e = l; e < epg; e += 64) {
      int s2 = ei[g * epg + e] - (int)nb;
      int d2 = ei[E + g * epg + e] - (int)nb;
      float as0 = s_a0[wv][s2], as1 = 1.f - as0;
      float ad0 = s_a0[wv][d2], ad1 = 1.f - ad0;
      c00 = fmaf(as0, ad0, c00); c01 = fmaf(as0, ad1, c01);
      c10 = fmaf(as1, ad0, c10); c11 = fmaf(as1, ad1, c11);
    }
    #pragma unroll
    for (int m = 1; m <= 32; m <<= 1) {
      c00 += __shfl_xor(c00, m, 64); c01 += __shfl_xor(c01, m, 64);
      c10 += __shfl_xor(c10, m, 64); c11 += __shfl_xor(c11, m, 64);
    }
    if (l == 0) {
      float d0 = c00 / fmaxf(fabsf(c00) + fabsf(c01), 1e-12f);
      float d1 = c11 / fmaxf(fabsf(c10) + fabsf(c11), 1e-12f);
      float pen = 0.5f * ((d0 - 1.f) * (d0 - 1.f) + (d1 - 1.f) * (d1 - 1.f));
      float kl = (0.5f * vSLN2 * r2acc + (float)NPG * tv) / (float)(NPG * HN);
      ws[g]                 = kl;
      ws[(size_t)G + g]     = pen;
      ws[2 * (size_t)G + g] = vpres * (1.0f / NPG);
    }
  }
}

// deterministic fixed-order reduction of the 3 per-graph scalar arrays
__global__ __launch_bounds__(1024) void gib_final(const float* __restrict__ ws,
                                                  float* __restrict__ out,
                                                  int G, long base)
{
  __shared__ float red[3][16];
  const int t = threadIdx.x, w = t >> 6, lid = t & 63;
  float s0 = 0.f, s1 = 0.f, s2 = 0.f;
  for (int i = t; i < G; i += 1024) {
    s0 += ws[(size_t)G + i];       // pos_penalty
    s1 += ws[i];                   // kl
    s2 += ws[2 * (size_t)G + i];   // preserve
  }
  #pragma unroll
  for (int m = 1; m <= 32; m <<= 1) {
    s0 += __shfl_xor(s0, m, 64);
    s1 += __shfl_xor(s1, m, 64);
    s2 += __shfl_xor(s2, m, 64);
  }
  if (lid == 0) { red[0][w] = s0; red[1][w] = s1; red[2][w] = s2; }
  __syncthreads();
  if (t == 0) {
    float r0 = 0.f, r1 = 0.f, r2 = 0.f;
    for (int i = 0; i < 16; ++i) { r0 += red[0][i]; r1 += red[1][i]; r2 += red[2][i]; }
    out[base + 0] = r0 / (float)G;
    out[base + 1] = r1 / (float)G;
    out[base + 2] = r2 / (float)G;
  }
}

extern "C" void kernel_launch(void* const* d_in, const int* in_sizes, int n_in,
                              void* d_out, int out_size, void* d_ws, size_t ws_size,
                              hipStream_t stream)
{
  const float* x  = (const float*)d_in[0];
  const float* W1 = (const float*)d_in[1];
  const float* b1 = (const float*)d_in[2];
  const float* W2 = (const float*)d_in[3];
  const float* b2 = (const float*)d_in[4];
  const float* gn = (const float*)d_in[5];
  const float* un = (const float*)d_in[6];
  const int*   ei = (const int*)d_in[7];
  float* out = (float*)d_out;
  float* ws  = (float*)d_ws;

  const long N = (long)in_sizes[0] / HN;
  const int  G = (int)(N / NPG);
  const long E = (long)in_sizes[7] / 2;
  const int epg = (int)(E / G);

  const int nblocks = (G + NW * SPW - 1) / (NW * SPW);   // 32768/64 = 512
  hipLaunchKernelGGL(gib_main, dim3(nblocks), dim3(NT), 0, stream,
                     x, W1, b1, W2, b2, gn, un, ei, out, ws, G, E, epg);
  const long base = 2L * (long)G * HN + N;
  hipLaunchKernelGGL(gib_final, dim3(1), dim3(1024), 0, stream, ws, out, G, base);
}

// Round 8
// 763.484 us; speedup vs baseline: 2.3095x; 2.3095x over previous
//
#include <hip/hip_runtime.h>

#define HN  128
#define NPG 32
#define NT  512
#define NW  8      // waves per block; 1 wave == 1 graph
#define SPW 16     // graphs per wave (serial)
#define HK  64     // half feature width resident in LDS
#define SXH 68     // padded row stride (floats) for half tile

typedef float f4 __attribute__((ext_vector_type(4)));
typedef float f2 __attribute__((ext_vector_type(2)));

__device__ __forceinline__ float tanh_fast(float v) {
  // tanh(v) = 1 - 2/(1+exp(2v)); saturates gracefully at +-1
  return 1.0f - 2.0f / (1.0f + __expf(2.0f * v));
}

__global__ __launch_bounds__(NT, 2) void gib_main(
    const float* __restrict__ x,  const float* __restrict__ W1,
    const float* __restrict__ b1, const float* __restrict__ W2,
    const float* __restrict__ b2, const float* __restrict__ gn,
    const float* __restrict__ un, const int* __restrict__ ei,
    float* __restrict__ out, float* __restrict__ ws,
    int G, long E, int epg)
{
  const int t  = threadIdx.x;
  const int wv = t >> 6;
  const int l  = t & 63;
  const int ng = l & 3;    // node group: nodes ng+4i, i=0..7
  const int cg = l >> 2;   // col group: cols 8cg..8cg+7
  const int sr = l >> 4;   // staging row base (rows sr+4r)
  const int sc = l & 15;   // staging chunk

  __shared__ __align__(16) float W1s[HN * HN];          // 64 KB, slot-deinterleaved
  __shared__ __align__(16) float xs[NW][NPG * SXH];     // 8 x 8.7 KB half tiles
  __shared__ float s_lp[NW][NPG], s_a0[NW][NPG];

  const long GL = (long)G * HN;

  // ---- stage W1 once, column-chunk de-interleaved (r5-verified layout) ----
  #pragma unroll
  for (int r = 0; r < 8; ++r) {
    int s = r * NT + t;
    int k = s >> 5, gm = s & 31;
    int slot = ((gm & 1) << 4) | (gm >> 1);
    *(f4*)&W1s[k * HN + slot * 4] = *(const f4*)(W1 + s * 4);
  }
  __syncthreads();   // only block-wide barrier

  float* xh = &xs[wv][0];

  // persistent params (graph-independent, hoisted)
  const f4 b1A = *(const f4*)(b1 + 8 * cg);
  const f4 b1B = *(const f4*)(b1 + 8 * cg + 4);
  const f4 w2a = *(const f4*)(W2 + 16 * cg);
  const f4 w2b = *(const f4*)(W2 + 16 * cg + 4);
  const f4 w2c = *(const f4*)(W2 + 16 * cg + 8);
  const f4 w2d = *(const f4*)(W2 + 16 * cg + 12);
  const float b20 = b2[0], b21 = b2[1];

  const long gbase = ((long)blockIdx.x * NW + wv) * SPW;

  // ---- prologue: stage h0 (k 0..63) of first graph ----
  {
    const float* xg0 = x + gbase * NPG * HN;
    #pragma unroll
    for (int r = 0; r < 8; ++r) {
      int n = sr + 4 * r;
      f4 v = *(const f4*)(xg0 + n * HN + sc * 4);
      *(f4*)&xh[n * SXH + sc * 4] = v;
    }
  }

  for (int si = 0; si < SPW; ++si) {
    const long g = gbase + si;
    if (g >= G) break;
    const long nb = g * NPG;
    const float* xg = x + nb * HN;
    const float* ug = un + nb * HN;

    // ---- issue h1 prefetch (consumed after phase 0) ----
    f4 h1b[8];
    #pragma unroll
    for (int r = 0; r < 8; ++r)
      h1b[r] = *(const f4*)(xg + (sr + 4 * r) * HN + HK + sc * 4);

    // ================= MLP phase 0 (k 0..63), 8 nodes x 8 cols =================
    f4 accA[8], accB[8];
    #pragma unroll
    for (int i = 0; i < 8; ++i) { accA[i] = b1A; accB[i] = b1B; }
    #pragma unroll 4
    for (int kc = 0; kc < 16; ++kc) {
      f4 wA[4], wB[4];
      #pragma unroll
      for (int kk = 0; kk < 4; ++kk) {
        wA[kk] = *(const f4*)&W1s[(kc * 4 + kk) * HN + cg * 4];
        wB[kk] = *(const f4*)&W1s[(kc * 4 + kk) * HN + 64 + cg * 4];
      }
      #pragma unroll
      for (int i = 0; i < 8; ++i) {
        f4 xv = *(const f4*)&xh[(ng + 4 * i) * SXH + kc * 4];
        #pragma unroll
        for (int kk = 0; kk < 4; ++kk) {
          accA[i] += wA[kk] * xv[kk];
          accB[i] += wB[kk] * xv[kk];
        }
      }
    }

    // ---- overwrite tile with h1 ----
    #pragma unroll
    for (int r = 0; r < 8; ++r)
      *(f4*)&xh[(sr + 4 * r) * SXH + sc * 4] = h1b[r];

    // ================= MLP phase 1 (k 64..127) =================
    #pragma unroll 4
    for (int kc = 0; kc < 16; ++kc) {
      f4 wA[4], wB[4];
      #pragma unroll
      for (int kk = 0; kk < 4; ++kk) {
        wA[kk] = *(const f4*)&W1s[(HK + kc * 4 + kk) * HN + cg * 4];
        wB[kk] = *(const f4*)&W1s[(HK + kc * 4 + kk) * HN + 64 + cg * 4];
      }
      #pragma unroll
      for (int i = 0; i < 8; ++i) {
        f4 xv = *(const f4*)&xh[(ng + 4 * i) * SXH + kc * 4];
        #pragma unroll
        for (int kk = 0; kk < 4; ++kk) {
          accA[i] += wA[kk] * xv[kk];
          accB[i] += wB[kk] * xv[kk];
        }
      }
    }

    // ---- epilogue: tanh -> W2 -> per-node logits, reduce over 16 cg lanes ----
    float z0[8], z1[8];
    #pragma unroll
    for (int i = 0; i < 8; ++i) {
      float h0 = tanh_fast(accA[i][0]), h1 = tanh_fast(accA[i][1]);
      float h2 = tanh_fast(accA[i][2]), h3 = tanh_fast(accA[i][3]);
      float h4 = tanh_fast(accB[i][0]), h5 = tanh_fast(accB[i][1]);
      float h6 = tanh_fast(accB[i][2]), h7 = tanh_fast(accB[i][3]);
      float a = h0*w2a[0] + h1*w2a[2] + h2*w2b[0] + h3*w2b[2]
              + h4*w2c[0] + h5*w2c[2] + h6*w2d[0] + h7*w2d[2];
      float b = h0*w2a[1] + h1*w2a[3] + h2*w2b[1] + h3*w2b[3]
              + h4*w2c[1] + h5*w2c[3] + h6*w2d[1] + h7*w2d[3];
      #pragma unroll
      for (int m = 4; m <= 32; m <<= 1) {
        a += __shfl_xor(a, m, 64);
        b += __shfl_xor(b, m, 64);
      }
      z0[i] = a; z1[i] = b;
    }

    // ---- issue next graph's h0 prefetch (tile free after phase 1) ----
    f4 h0b[8];
    const bool more = (si + 1 < SPW) && (g + 1 < G);
    if (more) {
      const float* xn = x + (g + 1) * NPG * HN;
      #pragma unroll
      for (int r = 0; r < 8; ++r)
        h0b[r] = *(const f4*)(xn + (sr + 4 * r) * HN + sc * 4);
    }

    // ---- softmax + gumbel (replicated across cg; cg==0 writes) ----
    float vSLN = 0.f, vSLN2 = 0.f, vpres = 0.f;
    #pragma unroll
    for (int i = 0; i < 8; ++i) {
      const int n = ng + 4 * i;
      f2 gnr = *(const f2*)(gn + (nb + n) * 2);
      float za = z0[i] + b20, zb = z1[i] + b21;
      float zm = fmaxf(za, zb);
      float e0 = __expf(za - zm), e1 = __expf(zb - zm);
      float a0 = e0 / (e0 + e1), a1 = 1.f - a0;
      float q0 = a0 + gnr[0], q1 = a1 + gnr[1];
      float qm = fmaxf(q0, q1);
      float E0 = __expf(q0 - qm), E1 = __expf(q1 - qm);
      float lp = E0 / (E0 + E1), ln = 1.f - lp;
      if (cg == 0) { s_lp[wv][n] = lp; s_a0[wv][n] = a0; }
      vSLN += ln; vSLN2 += ln * ln; vpres += (a0 > 0.5f) ? 1.f : 0.f;
    }
    vSLN  += __shfl_xor(vSLN, 1, 64);  vSLN  += __shfl_xor(vSLN, 2, 64);
    vSLN2 += __shfl_xor(vSLN2, 1, 64); vSLN2 += __shfl_xor(vSLN2, 2, 64);
    vpres += __shfl_xor(vpres, 1, 64); vpres += __shfl_xor(vpres, 2, 64);

    if (l < NPG)
      out[2 * GL + nb + l] = (s_lp[wv][l] > 0.5f) ? 1.0f : 0.0f;   // active

    // ---- stats from global x (L2-hot); lane owns features 2l,2l+1 ----
    f2 mu, sd, iv;
    float r2acc;
    {
      float s10 = 0.f, s11 = 0.f, s20 = 0.f, s21 = 0.f;
      #pragma unroll
      for (int n = 0; n < NPG; ++n) {
        f2 v = *(const f2*)(xg + n * HN + 2 * l);
        s10 += v[0]; s11 += v[1];
        s20 = fmaf(v[0], v[0], s20);
        s21 = fmaf(v[1], v[1], s21);
      }
      float m0 = s10 * (1.f / NPG), m1 = s11 * (1.f / NPG);
      float v0 = fmaxf((s20 - s10 * m0) * (1.f / (NPG - 1)), 0.f);
      float v1 = fmaxf((s21 - s11 * m1) * (1.f / (NPG - 1)), 0.f);
      float sd0 = sqrtf(v0), sd1 = sqrtf(v1);
      float in0 = 1.f / (sd0 + 1e-7f), in1 = 1.f / (sd1 + 1e-7f);
      mu[0] = m0; mu[1] = m1; sd[0] = sd0; sd[1] = sd1;
      iv[0] = in0 * in0; iv[1] = in1 * in1;
      f2 ge; ge[0] = s10; ge[1] = s11;
      *(f2*)&out[g * HN + 2 * l] = ge;              // graph_emb
      float r0 = sd0 * in0, r1 = sd1 * in1;
      float rr = r0 * r0 + r1 * r1;
      #pragma unroll
      for (int m = 1; m <= 32; m <<= 1) rr += __shfl_xor(rr, m, 64);
      r2acc = rr;
    }

    // ---- T2 + noisy_emb (x, un from global) ----
    float tv = 0.f, A0 = 0.f, A1 = 0.f, B0 = 0.f, B1 = 0.f;
    #pragma unroll 8
    for (int n = 0; n < NPG; ++n) {
      f2 xv = *(const f2*)(xg + n * HN + 2 * l);
      f2 uv = *(const f2*)(ug + n * HN + 2 * l);
      float lpn = s_lp[wv][n];
      float lnn = 1.f - lpn;
      float d0 = xv[0] - mu[0], d1 = xv[1] - mu[1];
      tv = fmaf(lpn * lpn, fmaf(d0 * d0, iv[0], d1 * d1 * iv[1]), tv);
      A0 = fmaf(lpn, xv[0], A0); A1 = fmaf(lpn, xv[1], A1);
      B0 = fmaf(lnn, uv[0], B0); B1 = fmaf(lnn, uv[1], B1);
    }
    {
      f2 ne;
      ne[0] = fmaf(mu[0], vSLN, A0) + sd[0] * B0;
      ne[1] = fmaf(mu[1], vSLN, A1) + sd[1] * B1;
      *(f2*)&out[GL + g * HN + 2 * l] = ne;        // noisy_emb
    }
    #pragma unroll
    for (int m = 1; m <= 32; m <<= 1) tv += __shfl_xor(tv, m, 64);

    // ---- edges -> 2x2 adjacency ----
    float c00 = 0.f, c01 = 0.f, c10 = 0.f, c11 = 0.f;
    for (int e = l; e < epg; e += 64) {
      int s2 = ei[g * epg + e] - (int)nb;
      int d2 = ei[E + g * epg + e] - (int)nb;
      float as0 = s_a0[wv][s2], as1 = 1.f - as0;
      float ad0 = s_a0[wv][d2], ad1 = 1.f - ad0;
      c00 = fmaf(as0, ad0, c00); c01 = fmaf(as0, ad1, c01);
      c10 = fmaf(as1, ad0, c10); c11 = fmaf(as1, ad1, c11);
    }
    #pragma unroll
    for (int m = 1; m <= 32; m <<= 1) {
      c00 += __shfl_xor(c00, m, 64); c01 += __shfl_xor(c01, m, 64);
      c10 += __shfl_xor(c10, m, 64); c11 += __shfl_xor(c11, m, 64);
    }
    if (l == 0) {
      float d0 = c00 / fmaxf(fabsf(c00) + fabsf(c01), 1e-12f);
      float d1 = c11 / fmaxf(fabsf(c10) + fabsf(c11), 1e-12f);
      float pen = 0.5f * ((d0 - 1.f) * (d0 - 1.f) + (d1 - 1.f) * (d1 - 1.f));
      float kl = (0.5f * vSLN2 * r2acc + (float)NPG * tv) / (float)(NPG * HN);
      ws[g]                 = kl;
      ws[(size_t)G + g]     = pen;
      ws[2 * (size_t)G + g] = vpres * (1.0f / NPG);
    }

    // ---- stage next graph's h0 ----
    if (more) {
      #pragma unroll
      for (int r = 0; r < 8; ++r)
        *(f4*)&xh[(sr + 4 * r) * SXH + sc * 4] = h0b[r];
    }
  }
}

// deterministic fixed-order reduction of the 3 per-graph scalar arrays
__global__ __launch_bounds__(1024) void gib_final(const float* __restrict__ ws,
                                                  float* __restrict__ out,
                                                  int G, long base)
{
  __shared__ float red[3][16];
  const int t = threadIdx.x, w = t >> 6, lid = t & 63;
  float s0 = 0.f, s1 = 0.f, s2 = 0.f;
  for (int i = t; i < G; i += 1024) {
    s0 += ws[(size_t)G + i];       // pos_penalty
    s1 += ws[i];                   // kl
    s2 += ws[2 * (size_t)G + i];   // preserve
  }
  #pragma unroll
  for (int m = 1; m <= 32; m <<= 1) {
    s0 += __shfl_xor(s0, m, 64);
    s1 += __shfl_xor(s1, m, 64);
    s2 += __shfl_xor(s2, m, 64);
  }
  if (lid == 0) { red[0][w] = s0; red[1][w] = s1; red[2][w] = s2; }
  __syncthreads();
  if (t == 0) {
    float r0 = 0.f, r1 = 0.f, r2 = 0.f;
    for (int i = 0; i < 16; ++i) { r0 += red[0][i]; r1 += red[1][i]; r2 += red[2][i]; }
    out[base + 0] = r0 / (float)G;
    out[base + 1] = r1 / (float)G;
    out[base + 2] = r2 / (float)G;
  }
}

extern "C" void kernel_launch(void* const* d_in, const int* in_sizes, int n_in,
                              void* d_out, int out_size, void* d_ws, size_t ws_size,
                              hipStream_t stream)
{
  const float* x  = (const float*)d_in[0];
  const float* W1 = (const float*)d_in[1];
  const float* b1 = (const float*)d_in[2];
  const float* W2 = (const float*)d_in[3];
  const float* b2 = (const float*)d_in[4];
  const float* gn = (const float*)d_in[5];
  const float* un = (const float*)d_in[6];
  const int*   ei = (const int*)d_in[7];
  float* out = (float*)d_out;
  float* ws  = (float*)d_ws;

  const long N = (long)in_sizes[0] / HN;
  const int  G = (int)(N / NPG);
  const long E = (long)in_sizes[7] / 2;
  const int epg = (int)(E / G);

  const int nblocks = (G + NW * SPW - 1) / (NW * SPW);   // 32768/128 = 256
  hipLaunchKernelGGL(gib_main, dim3(nblocks), dim3(NT), 0, stream,
                     x, W1, b1, W2, b2, gn, un, ei, out, ws, G, E, epg);
  const long base = 2L * (long)G * HN + N;
  hipLaunchKernelGGL(gib_final, dim3(1), dim3(1024), 0, stream, ws, out, G, base);
}

// Round 9
// 760.998 us; speedup vs baseline: 2.3170x; 1.0033x over previous
//
#include <hip/hip_runtime.h>

#define HN  128
#define NPG 32
#define NT  512
#define NW  8      // waves per block; 1 wave == 1 graph
#define SPW 16     // graphs per wave (serial)
#define HK  64     // half feature width resident in LDS
#define SXH 68     // padded row stride (floats) for half tile

typedef float f4 __attribute__((ext_vector_type(4)));
typedef float f2 __attribute__((ext_vector_type(2)));

__device__ __forceinline__ float tanh_fast(float v) {
  // tanh(v) = 1 - 2/(1+exp(2v)); saturates gracefully at +-1
  return 1.0f - 2.0f / (1.0f + __expf(2.0f * v));
}

__global__ __attribute__((amdgpu_flat_work_group_size(NT, NT), amdgpu_waves_per_eu(2)))
void gib_main(
    const float* __restrict__ x,  const float* __restrict__ W1,
    const float* __restrict__ b1, const float* __restrict__ W2,
    const float* __restrict__ b2, const float* __restrict__ gn,
    const float* __restrict__ un, const int* __restrict__ ei,
    float* __restrict__ out, float* __restrict__ ws,
    int G, long E, int epg)
{
  const int t  = threadIdx.x;
  const int wv = t >> 6;
  const int l  = t & 63;
  const int ng = l & 3;    // node group: nodes ng+4i, i=0..7
  const int cg = l >> 2;   // col group: cols 8cg..8cg+7
  const int sr = l >> 4;   // staging row base (rows sr+4r)
  const int sc = l & 15;   // staging chunk

  __shared__ __align__(16) float W1s[HN * HN];          // 64 KB, slot-deinterleaved
  __shared__ __align__(16) float xs[NW][NPG * SXH];     // 8 x 8.7 KB half tiles
  __shared__ float s_lp[NW][NPG], s_a0[NW][NPG];

  const long GL = (long)G * HN;

  // ---- stage W1 once, column-chunk de-interleaved (r5-verified layout) ----
  #pragma unroll
  for (int r = 0; r < 8; ++r) {
    int s = r * NT + t;
    int k = s >> 5, gm = s & 31;
    int slot = ((gm & 1) << 4) | (gm >> 1);
    *(f4*)&W1s[k * HN + slot * 4] = *(const f4*)(W1 + s * 4);
  }
  __syncthreads();   // only block-wide barrier

  float* xh = &xs[wv][0];

  // persistent params (graph-independent, hoisted)
  const f4 b1A = *(const f4*)(b1 + 8 * cg);
  const f4 b1B = *(const f4*)(b1 + 8 * cg + 4);
  const f4 w2a = *(const f4*)(W2 + 16 * cg);
  const f4 w2b = *(const f4*)(W2 + 16 * cg + 4);
  const f4 w2c = *(const f4*)(W2 + 16 * cg + 8);
  const f4 w2d = *(const f4*)(W2 + 16 * cg + 12);
  const float b20 = b2[0], b21 = b2[1];

  const long gbase = ((long)blockIdx.x * NW + wv) * SPW;

  // ---- prologue: stage h0 (k 0..63) of first graph ----
  {
    const float* xg0 = x + gbase * NPG * HN;
    #pragma unroll
    for (int r = 0; r < 8; ++r) {
      int n = sr + 4 * r;
      f4 v = *(const f4*)(xg0 + n * HN + sc * 4);
      *(f4*)&xh[n * SXH + sc * 4] = v;
    }
  }

  for (int si = 0; si < SPW; ++si) {
    const long g = gbase + si;
    if (g >= G) break;
    const long nb = g * NPG;
    const float* xg = x + nb * HN;
    const float* ug = un + nb * HN;

    // ---- issue h1 prefetch (consumed after phase 0) ----
    f4 h1b[8];
    #pragma unroll
    for (int r = 0; r < 8; ++r)
      h1b[r] = *(const f4*)(xg + (sr + 4 * r) * HN + HK + sc * 4);

    // ================= MLP phase 0 (k 0..63), 8 nodes x 8 cols =================
    f4 accA[8], accB[8];
    #pragma unroll
    for (int i = 0; i < 8; ++i) { accA[i] = b1A; accB[i] = b1B; }
    #pragma unroll 4
    for (int kc = 0; kc < 16; ++kc) {
      f4 wA[4], wB[4];
      #pragma unroll
      for (int kk = 0; kk < 4; ++kk) {
        wA[kk] = *(const f4*)&W1s[(kc * 4 + kk) * HN + cg * 4];
        wB[kk] = *(const f4*)&W1s[(kc * 4 + kk) * HN + 64 + cg * 4];
      }
      #pragma unroll
      for (int i = 0; i < 8; ++i) {
        f4 xv = *(const f4*)&xh[(ng + 4 * i) * SXH + kc * 4];
        #pragma unroll
        for (int kk = 0; kk < 4; ++kk) {
          accA[i] += wA[kk] * xv[kk];
          accB[i] += wB[kk] * xv[kk];
        }
      }
    }

    // ---- overwrite tile with h1 ----
    #pragma unroll
    for (int r = 0; r < 8; ++r)
      *(f4*)&xh[(sr + 4 * r) * SXH + sc * 4] = h1b[r];

    // ================= MLP phase 1 (k 64..127) =================
    #pragma unroll 4
    for (int kc = 0; kc < 16; ++kc) {
      f4 wA[4], wB[4];
      #pragma unroll
      for (int kk = 0; kk < 4; ++kk) {
        wA[kk] = *(const f4*)&W1s[(HK + kc * 4 + kk) * HN + cg * 4];
        wB[kk] = *(const f4*)&W1s[(HK + kc * 4 + kk) * HN + 64 + cg * 4];
      }
      #pragma unroll
      for (int i = 0; i < 8; ++i) {
        f4 xv = *(const f4*)&xh[(ng + 4 * i) * SXH + kc * 4];
        #pragma unroll
        for (int kk = 0; kk < 4; ++kk) {
          accA[i] += wA[kk] * xv[kk];
          accB[i] += wB[kk] * xv[kk];
        }
      }
    }

    // ---- epilogue: tanh -> W2 -> per-node logits, reduce over 16 cg lanes ----
    float z0[8], z1[8];
    #pragma unroll
    for (int i = 0; i < 8; ++i) {
      float h0 = tanh_fast(accA[i][0]), h1 = tanh_fast(accA[i][1]);
      float h2 = tanh_fast(accA[i][2]), h3 = tanh_fast(accA[i][3]);
      float h4 = tanh_fast(accB[i][0]), h5 = tanh_fast(accB[i][1]);
      float h6 = tanh_fast(accB[i][2]), h7 = tanh_fast(accB[i][3]);
      float a = h0*w2a[0] + h1*w2a[2] + h2*w2b[0] + h3*w2b[2]
              + h4*w2c[0] + h5*w2c[2] + h6*w2d[0] + h7*w2d[2];
      float b = h0*w2a[1] + h1*w2a[3] + h2*w2b[1] + h3*w2b[3]
              + h4*w2c[1] + h5*w2c[3] + h6*w2d[1] + h7*w2d[3];
      #pragma unroll
      for (int m = 4; m <= 32; m <<= 1) {
        a += __shfl_xor(a, m, 64);
        b += __shfl_xor(b, m, 64);
      }
      z0[i] = a; z1[i] = b;
    }

    // ---- issue next graph's h0 prefetch (tile free after phase 1) ----
    f4 h0b[8];
    const bool more = (si + 1 < SPW) && (g + 1 < G);
    if (more) {
      const float* xn = x + (g + 1) * NPG * HN;
      #pragma unroll
      for (int r = 0; r < 8; ++r)
        h0b[r] = *(const f4*)(xn + (sr + 4 * r) * HN + sc * 4);
    }

    // ---- softmax + gumbel (replicated across cg; cg==0 writes) ----
    float vSLN = 0.f, vSLN2 = 0.f, vpres = 0.f;
    #pragma unroll
    for (int i = 0; i < 8; ++i) {
      const int n = ng + 4 * i;
      f2 gnr = *(const f2*)(gn + (nb + n) * 2);
      float za = z0[i] + b20, zb = z1[i] + b21;
      float zm = fmaxf(za, zb);
      float e0 = __expf(za - zm), e1 = __expf(zb - zm);
      float a0 = e0 / (e0 + e1), a1 = 1.f - a0;
      float q0 = a0 + gnr[0], q1 = a1 + gnr[1];
      float qm = fmaxf(q0, q1);
      float E0 = __expf(q0 - qm), E1 = __expf(q1 - qm);
      float lp = E0 / (E0 + E1), ln = 1.f - lp;
      if (cg == 0) { s_lp[wv][n] = lp; s_a0[wv][n] = a0; }
      vSLN += ln; vSLN2 += ln * ln; vpres += (a0 > 0.5f) ? 1.f : 0.f;
    }
    vSLN  += __shfl_xor(vSLN, 1, 64);  vSLN  += __shfl_xor(vSLN, 2, 64);
    vSLN2 += __shfl_xor(vSLN2, 1, 64); vSLN2 += __shfl_xor(vSLN2, 2, 64);
    vpres += __shfl_xor(vpres, 1, 64); vpres += __shfl_xor(vpres, 2, 64);

    if (l < NPG)
      out[2 * GL + nb + l] = (s_lp[wv][l] > 0.5f) ? 1.0f : 0.0f;   // active

    // ---- stats from global x (L2-hot); lane owns features 2l,2l+1 ----
    f2 mu, sd, iv;
    float r2acc;
    {
      float s10 = 0.f, s11 = 0.f, s20 = 0.f, s21 = 0.f;
      #pragma unroll
      for (int n = 0; n < NPG; ++n) {
        f2 v = *(const f2*)(xg + n * HN + 2 * l);
        s10 += v[0]; s11 += v[1];
        s20 = fmaf(v[0], v[0], s20);
        s21 = fmaf(v[1], v[1], s21);
      }
      float m0 = s10 * (1.f / NPG), m1 = s11 * (1.f / NPG);
      float v0 = fmaxf((s20 - s10 * m0) * (1.f / (NPG - 1)), 0.f);
      float v1 = fmaxf((s21 - s11 * m1) * (1.f / (NPG - 1)), 0.f);
      float sd0 = sqrtf(v0), sd1 = sqrtf(v1);
      float in0 = 1.f / (sd0 + 1e-7f), in1 = 1.f / (sd1 + 1e-7f);
      mu[0] = m0; mu[1] = m1; sd[0] = sd0; sd[1] = sd1;
      iv[0] = in0 * in0; iv[1] = in1 * in1;
      f2 ge; ge[0] = s10; ge[1] = s11;
      *(f2*)&out[g * HN + 2 * l] = ge;              // graph_emb
      float r0 = sd0 * in0, r1 = sd1 * in1;
      float rr = r0 * r0 + r1 * r1;
      #pragma unroll
      for (int m = 1; m <= 32; m <<= 1) rr += __shfl_xor(rr, m, 64);
      r2acc = rr;
    }

    // ---- T2 + noisy_emb (x, un from global) ----
    float tv = 0.f, A0 = 0.f, A1 = 0.f, B0 = 0.f, B1 = 0.f;
    #pragma unroll 8
    for (int n = 0; n < NPG; ++n) {
      f2 xv = *(const f2*)(xg + n * HN + 2 * l);
      f2 uv = *(const f2*)(ug + n * HN + 2 * l);
      float lpn = s_lp[wv][n];
      float lnn = 1.f - lpn;
      float d0 = xv[0] - mu[0], d1 = xv[1] - mu[1];
      tv = fmaf(lpn * lpn, fmaf(d0 * d0, iv[0], d1 * d1 * iv[1]), tv);
      A0 = fmaf(lpn, xv[0], A0); A1 = fmaf(lpn, xv[1], A1);
      B0 = fmaf(lnn, uv[0], B0); B1 = fmaf(lnn, uv[1], B1);
    }
    {
      f2 ne;
      ne[0] = fmaf(mu[0], vSLN, A0) + sd[0] * B0;
      ne[1] = fmaf(mu[1], vSLN, A1) + sd[1] * B1;
      *(f2*)&out[GL + g * HN + 2 * l] = ne;        // noisy_emb
    }
    #pragma unroll
    for (int m = 1; m <= 32; m <<= 1) tv += __shfl_xor(tv, m, 64);

    // ---- edges -> 2x2 adjacency ----
    float c00 = 0.f, c01 = 0.f, c10 = 0.f, c11 = 0.f;
    for (int e = l; e < epg; e += 64) {
      int s2 = ei[g * epg + e] - (int)nb;
      int d2 = ei[E + g * epg + e] - (int)nb;
      float as0 = s_a0[wv][s2], as1 = 1.f - as0;
      float ad0 = s_a0[wv][d2], ad1 = 1.f - ad0;
      c00 = fmaf(as0, ad0, c00); c01 = fmaf(as0, ad1, c01);
      c10 = fmaf(as1, ad0, c10); c11 = fmaf(as1, ad1, c11);
    }
    #pragma unroll
    for (int m = 1; m <= 32; m <<= 1) {
      c00 += __shfl_xor(c00, m, 64); c01 += __shfl_xor(c01, m, 64);
      c10 += __shfl_xor(c10, m, 64); c11 += __shfl_xor(c11, m, 64);
    }
    if (l == 0) {
      float d0 = c00 / fmaxf(fabsf(c00) + fabsf(c01), 1e-12f);
      float d1 = c11 / fmaxf(fabsf(c10) + fabsf(c11), 1e-12f);
      float pen = 0.5f * ((d0 - 1.f) * (d0 - 1.f) + (d1 - 1.f) * (d1 - 1.f));
      float kl = (0.5f * vSLN2 * r2acc + (float)NPG * tv) / (float)(NPG * HN);
      ws[g]                 = kl;
      ws[(size_t)G + g]     = pen;
      ws[2 * (size_t)G + g] = vpres * (1.0f / NPG);
    }

    // ---- stage next graph's h0 ----
    if (more) {
      #pragma unroll
      for (int r = 0; r < 8; ++r)
        *(f4*)&xh[(sr + 4 * r) * SXH + sc * 4] = h0b[r];
    }
  }
}

// deterministic fixed-order reduction of the 3 per-graph scalar arrays
__global__ __launch_bounds__(1024) void gib_final(const float* __restrict__ ws,
                                                  float* __restrict__ out,
                                                  int G, long base)
{
  __shared__ float red[3][16];
  const int t = threadIdx.x, w = t >> 6, lid = t & 63;
  float s0 = 0.f, s1 = 0.f, s2 = 0.f;
  for (int i = t; i < G; i += 1024) {
    s0 += ws[(size_t)G + i];       // pos_penalty
    s1 += ws[i];                   // kl
    s2 += ws[2 * (size_t)G + i];   // preserve
  }
  #pragma unroll
  for (int m = 1; m <= 32; m <<= 1) {
    s0 += __shfl_xor(s0, m, 64);
    s1 += __shfl_xor(s1, m, 64);
    s2 += __shfl_xor(s2, m, 64);
  }
  if (lid == 0) { red[0][w] = s0; red[1][w] = s1; red[2][w] = s2; }
  __syncthreads();
  if (t == 0) {
    float r0 = 0.f, r1 = 0.f, r2 = 0.f;
    for (int i = 0; i < 16; ++i) { r0 += red[0][i]; r1 += red[1][i]; r2 += red[2][i]; }
    out[base + 0] = r0 / (float)G;
    out[base + 1] = r1 / (float)G;
    out[base + 2] = r2 / (float)G;
  }
}

extern "C" void kernel_launch(void* const* d_in, const int* in_sizes, int n_in,
                              void* d_out, int out_size, void* d_ws, size_t ws_size,
                              hipStream_t stream)
{
  const float* x  = (const float*)d_in[0];
  const float* W1 = (const float*)d_in[1];
  const float* b1 = (const float*)d_in[2];
  const float* W2 = (const float*)d_in[3];
  const float* b2 = (const float*)d_in[4];
  const float* gn = (const float*)d_in[5];
  const float* un = (const float*)d_in[6];
  const int*   ei = (const int*)d_in[7];
  float* out = (float*)d_out;
  float* ws  = (float*)d_ws;

  const long N = (long)in_sizes[0] / HN;
  const int  G = (int)(N / NPG);
  const long E = (long)in_sizes[7] / 2;
  const int epg = (int)(E / G);

  const int nblocks = (G + NW * SPW - 1) / (NW * SPW);   // 32768/128 = 256
  hipLaunchKernelGGL(gib_main, dim3(nblocks), dim3(NT), 0, stream,
                     x, W1, b1, W2, b2, gn, un, ei, out, ws, G, E, epg);
  const long base = 2L * (long)G * HN + N;
  hipLaunchKernelGGL(gib_final, dim3(1), dim3(1024), 0, stream, ws, out, G, base);
}

// Round 10
// 650.521 us; speedup vs baseline: 2.7105x; 1.1698x over previous
//
#include <hip/hip_runtime.h>

#define HN  128
#define NPG 32
#define NT  512
#define NW  8      // waves per block; 1 wave == 1 graph
#define SPW 16     // graphs per wave (serial)
#define HK  64     // half feature width resident in LDS
#define SXH 68     // padded row stride (floats) for half tile

typedef float f4 __attribute__((ext_vector_type(4)));
typedef float f2 __attribute__((ext_vector_type(2)));

__device__ __forceinline__ float tanh_fast(float v) {
  // tanh(v) = 1 - 2/(1+exp(2v)); saturates gracefully at +-1
  return 1.0f - 2.0f / (1.0f + __expf(2.0f * v));
}

__global__ __attribute__((amdgpu_flat_work_group_size(NT, NT), amdgpu_waves_per_eu(2)))
void gib_main(
    const float* __restrict__ x,  const float* __restrict__ W1,
    const float* __restrict__ b1, const float* __restrict__ W2,
    const float* __restrict__ b2, const float* __restrict__ gn,
    const float* __restrict__ un, const int* __restrict__ ei,
    float* __restrict__ out, float* __restrict__ ws,
    int G, long E, int epg)
{
  const int t  = threadIdx.x;
  const int wv = t >> 6;
  const int l  = t & 63;
  const int ng = l & 3;    // node group: nodes ng+4i, i=0..7
  const int cg = l >> 2;   // col group: cols 8cg..8cg+7
  const int sr = l >> 4;   // staging row base (rows sr+4r)
  const int sc = l & 15;   // staging chunk

  __shared__ __align__(16) float W1s[HN * HN];          // 64 KB, slot-deinterleaved
  __shared__ __align__(16) float xs[NW][NPG * SXH];     // 8 x 8.7 KB half tiles
  __shared__ float s_lp[NW][NPG], s_a0[NW][NPG];

  const long GL = (long)G * HN;

  // ---- stage W1 once, column-chunk de-interleaved ----
  #pragma unroll
  for (int r = 0; r < 8; ++r) {
    int s = r * NT + t;
    int k = s >> 5, gm = s & 31;
    int slot = ((gm & 1) << 4) | (gm >> 1);
    *(f4*)&W1s[k * HN + slot * 4] = *(const f4*)(W1 + s * 4);
  }
  __syncthreads();   // only block-wide barrier

  float* xh = &xs[wv][0];
  const float b20 = b2[0], b21 = b2[1];

  const long gbase = ((long)blockIdx.x * NW + wv) * SPW;

  // ---- prologue: stage h0 (k 0..63) of first graph ----
  {
    const float* xg0 = x + gbase * NPG * HN;
    #pragma unroll
    for (int r = 0; r < 8; ++r) {
      int n = sr + 4 * r;
      f4 v = *(const f4*)(xg0 + n * HN + sc * 4);
      *(f4*)&xh[n * SXH + sc * 4] = v;
    }
  }

  for (int si = 0; si < SPW; ++si) {
    const long g = gbase + si;
    if (g >= G) break;
    const long nb = g * NPG;
    const float* xg = x + nb * HN;
    const float* ug = un + nb * HN;

    // ================= MLP phase 0 (k 0..63), 8 nodes x 8 cols =================
    f4 accA[8], accB[8];
    {
      f4 b1A = *(const f4*)(b1 + 8 * cg);        // short-lived (L2-hot reload)
      f4 b1B = *(const f4*)(b1 + 8 * cg + 4);
      #pragma unroll
      for (int i = 0; i < 8; ++i) { accA[i] = b1A; accB[i] = b1B; }
    }
    #pragma unroll 4
    for (int kc = 0; kc < 16; ++kc) {
      f4 wA[4], wB[4];
      #pragma unroll
      for (int kk = 0; kk < 4; ++kk) {
        wA[kk] = *(const f4*)&W1s[(kc * 4 + kk) * HN + cg * 4];
        wB[kk] = *(const f4*)&W1s[(kc * 4 + kk) * HN + 64 + cg * 4];
      }
      #pragma unroll
      for (int i = 0; i < 8; ++i) {
        f4 xv = *(const f4*)&xh[(ng + 4 * i) * SXH + kc * 4];
        #pragma unroll
        for (int kk = 0; kk < 4; ++kk) {
          accA[i] += wA[kk] * xv[kk];
          accB[i] += wB[kk] * xv[kk];
        }
      }
    }

    // ---- h1 prefetch: issued only AFTER phase 0 (keeps peak liveness < 128) ----
    __builtin_amdgcn_sched_barrier(0);
    f4 h1b[8];
    #pragma unroll
    for (int r = 0; r < 8; ++r)
      h1b[r] = *(const f4*)(xg + (sr + 4 * r) * HN + HK + sc * 4);
    __builtin_amdgcn_sched_barrier(0);

    // ---- stats pass (global x, L2-hot) — covers h1b latency ----
    f2 mu, sd, iv;
    float r2acc;
    {
      float s10 = 0.f, s11 = 0.f, s20 = 0.f, s21 = 0.f;
      #pragma unroll
      for (int n = 0; n < NPG; ++n) {
        f2 v = *(const f2*)(xg + n * HN + 2 * l);
        s10 += v[0]; s11 += v[1];
        s20 = fmaf(v[0], v[0], s20);
        s21 = fmaf(v[1], v[1], s21);
      }
      float m0 = s10 * (1.f / NPG), m1 = s11 * (1.f / NPG);
      float v0 = fmaxf((s20 - s10 * m0) * (1.f / (NPG - 1)), 0.f);
      float v1 = fmaxf((s21 - s11 * m1) * (1.f / (NPG - 1)), 0.f);
      float sd0 = sqrtf(v0), sd1 = sqrtf(v1);
      float in0 = 1.f / (sd0 + 1e-7f), in1 = 1.f / (sd1 + 1e-7f);
      mu[0] = m0; mu[1] = m1; sd[0] = sd0; sd[1] = sd1;
      iv[0] = in0 * in0; iv[1] = in1 * in1;
      f2 ge; ge[0] = s10; ge[1] = s11;
      *(f2*)&out[g * HN + 2 * l] = ge;              // graph_emb
      float r0 = sd0 * in0, r1 = sd1 * in1;
      float rr = r0 * r0 + r1 * r1;
      #pragma unroll
      for (int m = 1; m <= 32; m <<= 1) rr += __shfl_xor(rr, m, 64);
      r2acc = rr;
    }

    // ---- overwrite tile with h1 ----
    #pragma unroll
    for (int r = 0; r < 8; ++r)
      *(f4*)&xh[(sr + 4 * r) * SXH + sc * 4] = h1b[r];

    // ================= MLP phase 1 (k 64..127) =================
    #pragma unroll 4
    for (int kc = 0; kc < 16; ++kc) {
      f4 wA[4], wB[4];
      #pragma unroll
      for (int kk = 0; kk < 4; ++kk) {
        wA[kk] = *(const f4*)&W1s[(HK + kc * 4 + kk) * HN + cg * 4];
        wB[kk] = *(const f4*)&W1s[(HK + kc * 4 + kk) * HN + 64 + cg * 4];
      }
      #pragma unroll
      for (int i = 0; i < 8; ++i) {
        f4 xv = *(const f4*)&xh[(ng + 4 * i) * SXH + kc * 4];
        #pragma unroll
        for (int kk = 0; kk < 4; ++kk) {
          accA[i] += wA[kk] * xv[kk];
          accB[i] += wB[kk] * xv[kk];
        }
      }
    }

    // ---- epilogue: tanh -> W2 (loaded here; disjoint from h1b live range) ----
    float z0[8], z1[8];
    {
      f4 w2a = *(const f4*)(W2 + 16 * cg);
      f4 w2b = *(const f4*)(W2 + 16 * cg + 4);
      f4 w2c = *(const f4*)(W2 + 16 * cg + 8);
      f4 w2d = *(const f4*)(W2 + 16 * cg + 12);
      #pragma unroll
      for (int i = 0; i < 8; ++i) {
        float h0 = tanh_fast(accA[i][0]), h1 = tanh_fast(accA[i][1]);
        float h2 = tanh_fast(accA[i][2]), h3 = tanh_fast(accA[i][3]);
        float h4 = tanh_fast(accB[i][0]), h5 = tanh_fast(accB[i][1]);
        float h6 = tanh_fast(accB[i][2]), h7 = tanh_fast(accB[i][3]);
        float a = h0*w2a[0] + h1*w2a[2] + h2*w2b[0] + h3*w2b[2]
                + h4*w2c[0] + h5*w2c[2] + h6*w2d[0] + h7*w2d[2];
        float b = h0*w2a[1] + h1*w2a[3] + h2*w2b[1] + h3*w2b[3]
                + h4*w2c[1] + h5*w2c[3] + h6*w2d[1] + h7*w2d[3];
        #pragma unroll
        for (int m = 4; m <= 32; m <<= 1) {
          a += __shfl_xor(a, m, 64);
          b += __shfl_xor(b, m, 64);
        }
        z0[i] = a; z1[i] = b;
      }
    }

    // ---- next graph's h0 prefetch (fenced both sides) ----
    __builtin_amdgcn_sched_barrier(0);
    f4 h0b[8];
    const bool more = (si + 1 < SPW) && (g + 1 < G);
    if (more) {
      const float* xn = x + (g + 1) * NPG * HN;
      #pragma unroll
      for (int r = 0; r < 8; ++r)
        h0b[r] = *(const f4*)(xn + (sr + 4 * r) * HN + sc * 4);
    }
    __builtin_amdgcn_sched_barrier(0);

    // ---- softmax + gumbel (replicated across cg; cg==0 writes) ----
    float vSLN = 0.f, vSLN2 = 0.f, vpres = 0.f;
    #pragma unroll
    for (int i = 0; i < 8; ++i) {
      const int n = ng + 4 * i;
      f2 gnr = *(const f2*)(gn + (nb + n) * 2);
      float za = z0[i] + b20, zb = z1[i] + b21;
      float zm = fmaxf(za, zb);
      float e0 = __expf(za - zm), e1 = __expf(zb - zm);
      float a0 = e0 / (e0 + e1), a1 = 1.f - a0;
      float q0 = a0 + gnr[0], q1 = a1 + gnr[1];
      float qm = fmaxf(q0, q1);
      float E0 = __expf(q0 - qm), E1 = __expf(q1 - qm);
      float lp = E0 / (E0 + E1), ln = 1.f - lp;
      if (cg == 0) { s_lp[wv][n] = lp; s_a0[wv][n] = a0; }
      vSLN += ln; vSLN2 += ln * ln; vpres += (a0 > 0.5f) ? 1.f : 0.f;
    }
    vSLN  += __shfl_xor(vSLN, 1, 64);  vSLN  += __shfl_xor(vSLN, 2, 64);
    vSLN2 += __shfl_xor(vSLN2, 1, 64); vSLN2 += __shfl_xor(vSLN2, 2, 64);
    vpres += __shfl_xor(vpres, 1, 64); vpres += __shfl_xor(vpres, 2, 64);

    if (l < NPG)
      out[2 * GL + nb + l] = (s_lp[wv][l] > 0.5f) ? 1.0f : 0.0f;   // active

    // ---- T2 + noisy_emb (x, un from global) ----
    float tv = 0.f, A0 = 0.f, A1 = 0.f, B0 = 0.f, B1 = 0.f;
    #pragma unroll 8
    for (int n = 0; n < NPG; ++n) {
      f2 xv = *(const f2*)(xg + n * HN + 2 * l);
      f2 uv = *(const f2*)(ug + n * HN + 2 * l);
      float lpn = s_lp[wv][n];
      float lnn = 1.f - lpn;
      float d0 = xv[0] - mu[0], d1 = xv[1] - mu[1];
      tv = fmaf(lpn * lpn, fmaf(d0 * d0, iv[0], d1 * d1 * iv[1]), tv);
      A0 = fmaf(lpn, xv[0], A0); A1 = fmaf(lpn, xv[1], A1);
      B0 = fmaf(lnn, uv[0], B0); B1 = fmaf(lnn, uv[1], B1);
    }
    {
      f2 ne;
      ne[0] = fmaf(mu[0], vSLN, A0) + sd[0] * B0;
      ne[1] = fmaf(mu[1], vSLN, A1) + sd[1] * B1;
      *(f2*)&out[GL + g * HN + 2 * l] = ne;        // noisy_emb
    }
    #pragma unroll
    for (int m = 1; m <= 32; m <<= 1) tv += __shfl_xor(tv, m, 64);

    // ---- edges -> 2x2 adjacency ----
    float c00 = 0.f, c01 = 0.f, c10 = 0.f, c11 = 0.f;
    for (int e = l; e < epg; e += 64) {
      int s2 = ei[g * epg + e] - (int)nb;
      int d2 = ei[E + g * epg + e] - (int)nb;
      float as0 = s_a0[wv][s2], as1 = 1.f - as0;
      float ad0 = s_a0[wv][d2], ad1 = 1.f - ad0;
      c00 = fmaf(as0, ad0, c00); c01 = fmaf(as0, ad1, c01);
      c10 = fmaf(as1, ad0, c10); c11 = fmaf(as1, ad1, c11);
    }
    #pragma unroll
    for (int m = 1; m <= 32; m <<= 1) {
      c00 += __shfl_xor(c00, m, 64); c01 += __shfl_xor(c01, m, 64);
      c10 += __shfl_xor(c10, m, 64); c11 += __shfl_xor(c11, m, 64);
    }
    if (l == 0) {
      float d0 = c00 / fmaxf(fabsf(c00) + fabsf(c01), 1e-12f);
      float d1 = c11 / fmaxf(fabsf(c10) + fabsf(c11), 1e-12f);
      float pen = 0.5f * ((d0 - 1.f) * (d0 - 1.f) + (d1 - 1.f) * (d1 - 1.f));
      float kl = (0.5f * vSLN2 * r2acc + (float)NPG * tv) / (float)(NPG * HN);
      ws[g]                 = kl;
      ws[(size_t)G + g]     = pen;
      ws[2 * (size_t)G + g] = vpres * (1.0f / NPG);
    }

    // ---- stage next graph's h0 ----
    if (more) {
      #pragma unroll
      for (int r = 0; r < 8; ++r)
        *(f4*)&xh[(sr + 4 * r) * SXH + sc * 4] = h0b[r];
    }
  }
}

// deterministic fixed-order reduction of the 3 per-graph scalar arrays
__global__ __launch_bounds__(1024) void gib_final(const float* __restrict__ ws,
                                                  float* __restrict__ out,
                                                  int G, long base)
{
  __shared__ float red[3][16];
  const int t = threadIdx.x, w = t >> 6, lid = t & 63;
  float s0 = 0.f, s1 = 0.f, s2 = 0.f;
  for (int i = t; i < G; i += 1024) {
    s0 += ws[(size_t)G + i];       // pos_penalty
    s1 += ws[i];                   // kl
    s2 += ws[2 * (size_t)G + i];   // preserve
  }
  #pragma unroll
  for (int m = 1; m <= 32; m <<= 1) {
    s0 += __shfl_xor(s0, m, 64);
    s1 += __shfl_xor(s1, m, 64);
    s2 += __shfl_xor(s2, m, 64);
  }
  if (lid == 0) { red[0][w] = s0; red[1][w] = s1; red[2][w] = s2; }
  __syncthreads();
  if (t == 0) {
    float r0 = 0.f, r1 = 0.f, r2 = 0.f;
    for (int i = 0; i < 16; ++i) { r0 += red[0][i]; r1 += red[1][i]; r2 += red[2][i]; }
    out[base + 0] = r0 / (float)G;
    out[base + 1] = r1 / (float)G;
    out[base + 2] = r2 / (float)G;
  }
}

extern "C" void kernel_launch(void* const* d_in, const int* in_sizes, int n_in,
                              void* d_out, int out_size, void* d_ws, size_t ws_size,
                              hipStream_t stream)
{
  const float* x  = (const float*)d_in[0];
  const float* W1 = (const float*)d_in[1];
  const float* b1 = (const float*)d_in[2];
  const float* W2 = (const float*)d_in[3];
  const float* b2 = (const float*)d_in[4];
  const float* gn = (const float*)d_in[5];
  const float* un = (const float*)d_in[6];
  const int*   ei = (const int*)d_in[7];
  float* out = (float*)d_out;
  float* ws  = (float*)d_ws;

  const long N = (long)in_sizes[0] / HN;
  const int  G = (int)(N / NPG);
  const long E = (long)in_sizes[7] / 2;
  const int epg = (int)(E / G);

  const int nblocks = (G + NW * SPW - 1) / (NW * SPW);   // 32768/128 = 256
  hipLaunchKernelGGL(gib_main, dim3(nblocks), dim3(NT), 0, stream,
                     x, W1, b1, W2, b2, gn, un, ei, out, ws, G, E, epg);
  const long base = 2L * (long)G * HN + N;
  hipLaunchKernelGGL(gib_final, dim3(1), dim3(1024), 0, stream, ws, out, G, base);
}